// Round 4
// baseline (390.002 us; speedup 1.0000x reference)
//
#include <hip/hip_runtime.h>
#include <hip/hip_bf16.h>

typedef __attribute__((ext_vector_type(8))) short bf16x8;
typedef __attribute__((ext_vector_type(4))) float f32x4;

#define HD 256   // hidden size (K of the big GEMM)
#define NB 32    // batch
#define NT 4096  // timesteps
#define NE 8192  // edges per graph
#define N2 512   // 2*H (N of the big GEMM)

static __device__ __forceinline__ unsigned short f2bf(float f) {
  unsigned int u = __float_as_uint(f);
  u += 0x7fff + ((u >> 16) & 1);  // round-to-nearest-even
  return (unsigned short)(u >> 16);
}
static __device__ __forceinline__ short4 cvt4(float4 a) {
  return make_short4((short)f2bf(a.x), (short)f2bf(a.y),
                     (short)f2bf(a.z), (short)f2bf(a.w));
}
static __device__ __forceinline__ float fast_tanh(float x) {
  x = fminf(15.f, fmaxf(-15.f, x));
  float e = __expf(x + x);
  return (e - 1.f) * __builtin_amdgcn_rcpf(e + 1.f);
}

// Fused prep:
//  blocks 0..255   : cvecT[n][b] = b_attn[n] + hidden[b] . W_attn[n][0:256]
//  blocks 256..383 : Wbf[n*256+k] = bf16(W_attn[n][256+k])   (one-time convert)
__global__ __launch_bounds__(256) void prep(
    const float* __restrict__ hidden, const float* __restrict__ Wattn,
    const float* __restrict__ battn, float* __restrict__ cvecT,
    short* __restrict__ Wbf) {
  const int tid = threadIdx.x;
  if (blockIdx.x < 256) {
    __shared__ float Ws[64 * 260];
    __shared__ float Hs[HD];
    const int chunk = blockIdx.x & 7;
    const int b = blockIdx.x >> 3;
#pragma unroll
    for (int it = 0; it < 16; ++it) {
      int f = it * 1024 + tid * 4;
      int i = f >> 8, k = f & 255;
      float4 w4 = *(const float4*)(Wattn + (chunk * 64 + i) * N2 + k);
      *(float4*)&Ws[i * 260 + k] = w4;
    }
    if (tid < 64)
      *(float4*)&Hs[tid * 4] = *(const float4*)(hidden + b * HD + tid * 4);
    __syncthreads();
    const int nl = tid >> 2;
    const int kb = (tid & 3) * 64;
    float sum = 0.f;
#pragma unroll
    for (int z = 0; z < 64; z += 4) {
      float4 h4 = *(const float4*)&Hs[kb + z];
      float4 w4 = *(const float4*)&Ws[nl * 260 + kb + z];
      sum = fmaf(h4.x, w4.x, sum);
      sum = fmaf(h4.y, w4.y, sum);
      sum = fmaf(h4.z, w4.z, sum);
      sum = fmaf(h4.w, w4.w, sum);
    }
    sum += __shfl_xor(sum, 1, 64);
    sum += __shfl_xor(sum, 2, 64);
    if ((tid & 3) == 0)
      cvecT[(chunk * 64 + nl) * NB + b] = sum + battn[chunk * 64 + nl];
  } else {
    int f = (blockIdx.x - 256) * 1024 + tid * 4;  // 0..131071 = n*256+k
    int n = f >> 8, k = f & 255;
    float4 w4 = *(const float4*)(Wattn + n * N2 + HD + k);
    *(short4*)(Wbf + f) = cvt4(w4);
  }
}

// scores[b][t] = sum_n v[n]*tanh(cvecT[n][b] + enc_row . Wbf[n])
// 128 rows/block, 4 col-passes of 32 cols/wave (breg[2][8] = 64 VGPRs, no
// dynamic register indexing anywhere -> no scratch). A staged in LDS with
// XOR swizzle (slot = (k>>3) ^ (r&31)) -> conflict-free ds_read_b128.
__global__ __launch_bounds__(256, 2) void score_gemm(
    const float* __restrict__ enc, const short* __restrict__ Wbf,
    const float* __restrict__ cvecT, const float* __restrict__ vvec,
    float* __restrict__ scores) {
  __shared__ short As[128 * 256];  // 64 KB, swizzled
  __shared__ float part[4][128];
  const int tid = threadIdx.x;
  const int w = tid >> 6, lane = tid & 63, q = lane >> 4, m = lane & 15;
  const long row0 = (long)blockIdx.x * 128;

  // ---- stage A (128 rows x 256 k) fp32 -> bf16, swizzled ----
  const float* src = enc + row0 * HD;
#pragma unroll
  for (int it = 0; it < 32; ++it) {
    int f = it * 1024 + tid * 4;
    float4 a4 = *(const float4*)(src + f);
    int r = f >> 8, k = f & 255;
    int slot = (k >> 3) ^ (r & 31);
    *(short4*)&As[(r * 32 + slot) * 8 + (k & 7)] = cvt4(a4);
  }
  __syncthreads();

  float rowacc[8][4];
#pragma unroll
  for (int rt = 0; rt < 8; ++rt)
#pragma unroll
    for (int j = 0; j < 4; ++j) rowacc[rt][j] = 0.f;

#pragma unroll 1
  for (int cc = 0; cc < 4; ++cc) {
    const int nb = cc * 128 + w * 32;  // wave's col base this pass
    bf16x8 breg[2][8];
    float vv[2];
    f32x4 cva[2], cvb[2];
#pragma unroll
    for (int c = 0; c < 2; ++c) {
      const int n = nb + c * 16 + m;
      const short* bp = Wbf + n * HD + q * 8;
#pragma unroll
      for (int kk = 0; kk < 8; ++kk) breg[c][kk] = *(const bf16x8*)(bp + kk * 32);
      vv[c] = vvec[n];
      cva[c] = *(const f32x4*)(cvecT + n * NB + q * 4);        // b = 4q+j
      cvb[c] = *(const f32x4*)(cvecT + n * NB + 16 + q * 4);   // b = 16+4q+j
    }
#pragma unroll
    for (int rt = 0; rt < 8; ++rt) {
      const int r = rt * 16 + m;
      const int rx = r & 31;
      f32x4 acc0 = {0.f, 0.f, 0.f, 0.f}, acc1 = {0.f, 0.f, 0.f, 0.f};
#pragma unroll
      for (int kk = 0; kk < 8; ++kk) {
        bf16x8 a = *(const bf16x8*)&As[(r * 32 + ((kk * 4 + q) ^ rx)) * 8];
        acc0 = __builtin_amdgcn_mfma_f32_16x16x32_bf16(a, breg[0][kk], acc0, 0, 0, 0);
        acc1 = __builtin_amdgcn_mfma_f32_16x16x32_bf16(a, breg[1][kk], acc1, 0, 0, 0);
      }
      // C/D layout: row = rt*16 + 4q+j, col = n(c,m); b = row & 31
      if (rt & 1) {  // compile-time: rt fully unrolled
#pragma unroll
        for (int j = 0; j < 4; ++j)
          rowacc[rt][j] += fast_tanh(acc0[j] + cvb[0][j]) * vv[0]
                         + fast_tanh(acc1[j] + cvb[1][j]) * vv[1];
      } else {
#pragma unroll
        for (int j = 0; j < 4; ++j)
          rowacc[rt][j] += fast_tanh(acc0[j] + cva[0][j]) * vv[0]
                         + fast_tanh(acc1[j] + cva[1][j]) * vv[1];
      }
    }
  }

  // ---- deferred reduction over the 16 m-lanes, then cross-wave combine ----
#pragma unroll
  for (int rt = 0; rt < 8; ++rt) {
#pragma unroll
    for (int j = 0; j < 4; ++j) {
      float e = rowacc[rt][j];
      e += __shfl_xor(e, 1, 64);
      e += __shfl_xor(e, 2, 64);
      e += __shfl_xor(e, 4, 64);
      e += __shfl_xor(e, 8, 64);
      if (m == 0) part[w][rt * 16 + 4 * q + j] = e;
    }
  }
  __syncthreads();
  if (tid < 128) {
    const long r = row0 + tid;  // flat row = t*NB + b
    scores[(r & 31) * NT + (r >> 5)] =
        part[0][tid] + part[1][tid] + part[2][tid] + part[3][tid];
  }
}

// softmax over T per batch row; writes wn = 0.1*softmax in-place; zeroes out[b]
__global__ __launch_bounds__(1024) void softmax_norm(
    float* __restrict__ sc, float* __restrict__ out) {
  __shared__ float rtmp[16];
  __shared__ float rres;
  const int b = blockIdx.x;
  const int tid = threadIdx.x;
  const int wid = tid >> 6, lane = tid & 63;
  float s[4];
  float mx = -1e30f;
#pragma unroll
  for (int p = 0; p < 4; ++p) {
    s[p] = sc[b * NT + tid + p * 1024];
    mx = fmaxf(mx, s[p]);
  }
#pragma unroll
  for (int d = 32; d >= 1; d >>= 1) mx = fmaxf(mx, __shfl_xor(mx, d, 64));
  if (lane == 0) rtmp[wid] = mx;
  __syncthreads();
  if (tid == 0) {
    float mm = rtmp[0];
#pragma unroll
    for (int i = 1; i < 16; ++i) mm = fmaxf(mm, rtmp[i]);
    rres = mm;
  }
  __syncthreads();
  mx = rres;
  float sm = 0.f;
#pragma unroll
  for (int p = 0; p < 4; ++p) {
    s[p] = __expf(s[p] - mx);
    sm += s[p];
  }
#pragma unroll
  for (int d = 32; d >= 1; d >>= 1) sm += __shfl_xor(sm, d, 64);
  if (lane == 0) rtmp[wid] = sm;
  __syncthreads();
  if (tid == 0) {
    float tt = 0.f;
#pragma unroll
    for (int i = 0; i < 16; ++i) tt += rtmp[i];
    rres = tt;
  }
  __syncthreads();
  const float scale = 0.1f / rres;
#pragma unroll
  for (int p = 0; p < 4; ++p) {
    int i = tid + p * 1024;
    sc[b * NT + i] = s[p] * scale;  // wn
    out[b * NT + i] = 0.f;          // zero-init for scatter
  }
}

// out[b][dst] += wn[b][src] for edges with dst != src+1 (global atomics)
__global__ __launch_bounds__(512) void scatter(
    const float* __restrict__ wn, const int* __restrict__ esrc,
    const int* __restrict__ edst, float* __restrict__ out) {
  const int b = blockIdx.x >> 4;
  const int e = (blockIdx.x & 15) * 512 + threadIdx.x;
  const int ss = esrc[b * NE + e];
  const int dd = edst[b * NE + e];
  if (dd != ss + 1) atomicAdd(out + b * NT + dd, wn[b * NT + ss]);
}

extern "C" void kernel_launch(void* const* d_in, const int* in_sizes, int n_in,
                              void* d_out, int out_size, void* d_ws, size_t ws_size,
                              hipStream_t stream) {
  const float* hidden = (const float*)d_in[0];
  const float* enc    = (const float*)d_in[1];
  const int*   esrc   = (const int*)d_in[2];
  const int*   edst   = (const int*)d_in[3];
  const float* Wattn  = (const float*)d_in[4];
  const float* battn  = (const float*)d_in[5];
  const float* vvec   = (const float*)d_in[6];
  float* out = (float*)d_out;

  char* ws = (char*)d_ws;
  float* cvecT  = (float*)ws;                    // 512*32*4   = 64 KB
  short* Wbf    = (short*)(ws + 65536);          // 512*256*2  = 256 KB
  float* scores = (float*)(ws + 65536 + 262144); // 32*4096*4  = 512 KB

  prep<<<384, 256, 0, stream>>>(hidden, Wattn, battn, cvecT, Wbf);
  score_gemm<<<(NB * NT) / 128, 256, 0, stream>>>(enc, Wbf, cvecT, vvec, scores);
  softmax_norm<<<NB, 1024, 0, stream>>>(scores, out);
  scatter<<<512, 512, 0, stream>>>(scores, esrc, edst, out);
}

// Round 5
// 309.166 us; speedup vs baseline: 1.2615x; 1.2615x over previous
//
#include <hip/hip_runtime.h>
#include <hip/hip_bf16.h>

typedef __attribute__((ext_vector_type(8))) short bf16x8;
typedef __attribute__((ext_vector_type(4))) float f32x4;

#define HD 256   // hidden size (K of the big GEMM)
#define NB 32    // batch
#define NT 4096  // timesteps
#define NE 8192  // edges per graph
#define N2 512   // 2*H (N of the big GEMM)

static __device__ __forceinline__ unsigned short f2bf(float f) {
  unsigned int u = __float_as_uint(f);
  u += 0x7fff + ((u >> 16) & 1);  // round-to-nearest-even
  return (unsigned short)(u >> 16);
}
static __device__ __forceinline__ short4 cvt4(float4 a) {
  return make_short4((short)f2bf(a.x), (short)f2bf(a.y),
                     (short)f2bf(a.z), (short)f2bf(a.w));
}
static __device__ __forceinline__ float fast_tanh(float x) {
  x = fminf(15.f, fmaxf(-15.f, x));
  float e = __expf(x + x);
  return (e - 1.f) * __builtin_amdgcn_rcpf(e + 1.f);
}

// Fused prep:
//  blocks 0..255   : cvecT[n][b] = b_attn[n] + hidden[b] . W_attn[n][0:256]
//  blocks 256..383 : Wbf[n*256+k] = bf16(W_attn[n][256+k])   (one-time convert)
__global__ __launch_bounds__(256) void prep(
    const float* __restrict__ hidden, const float* __restrict__ Wattn,
    const float* __restrict__ battn, float* __restrict__ cvecT,
    short* __restrict__ Wbf) {
  const int tid = threadIdx.x;
  if (blockIdx.x < 256) {
    __shared__ float Ws[64 * 260];
    __shared__ float Hs[HD];
    const int chunk = blockIdx.x & 7;
    const int b = blockIdx.x >> 3;
#pragma unroll
    for (int it = 0; it < 16; ++it) {
      int f = it * 1024 + tid * 4;
      int i = f >> 8, k = f & 255;
      float4 w4 = *(const float4*)(Wattn + (chunk * 64 + i) * N2 + k);
      *(float4*)&Ws[i * 260 + k] = w4;
    }
    if (tid < 64)
      *(float4*)&Hs[tid * 4] = *(const float4*)(hidden + b * HD + tid * 4);
    __syncthreads();
    const int nl = tid >> 2;
    const int kb = (tid & 3) * 64;
    float sum = 0.f;
#pragma unroll
    for (int z = 0; z < 64; z += 4) {
      float4 h4 = *(const float4*)&Hs[kb + z];
      float4 w4 = *(const float4*)&Ws[nl * 260 + kb + z];
      sum = fmaf(h4.x, w4.x, sum);
      sum = fmaf(h4.y, w4.y, sum);
      sum = fmaf(h4.z, w4.z, sum);
      sum = fmaf(h4.w, w4.w, sum);
    }
    sum += __shfl_xor(sum, 1, 64);
    sum += __shfl_xor(sum, 2, 64);
    if ((tid & 3) == 0)
      cvecT[(chunk * 64 + nl) * NB + b] = sum + battn[chunk * 64 + nl];
  } else {
    int f = (blockIdx.x - 256) * 1024 + tid * 4;  // 0..131071 = n*256+k
    int n = f >> 8, k = f & 255;
    float4 w4 = *(const float4*)(Wattn + n * N2 + HD + k);
    *(short4*)(Wbf + f) = cvt4(w4);
  }
}

// scores[b][t] = sum_n v[n]*tanh(cvecT[n][b] + enc_row . Wbf[n])
// 128 rows/block, 4 col-passes of 32 cols/wave (breg = 64 VGPRs). rt fully
// unrolled (static rowacc) but sched_barrier(0) per rt-iter stops the
// scheduler from hoisting all A-loads (R4's spill). launch_bounds(256,1):
// full 512-reg unified budget so nothing spills; LDS caps us at 2 blocks/CU.
__global__ __launch_bounds__(256, 1) void score_gemm(
    const float* __restrict__ enc, const short* __restrict__ Wbf,
    const float* __restrict__ cvecT, const float* __restrict__ vvec,
    float* __restrict__ scores) {
  __shared__ short As[128 * 256];  // 64 KB, swizzled
  __shared__ float part[4][128];
  const int tid = threadIdx.x;
  const int w = tid >> 6, lane = tid & 63, q = lane >> 4, m = lane & 15;
  const long row0 = (long)blockIdx.x * 128;

  // ---- stage A (128 rows x 256 k) fp32 -> bf16, swizzled ----
  const float* src = enc + row0 * HD;
#pragma unroll
  for (int it = 0; it < 32; ++it) {
    int f = it * 1024 + tid * 4;
    float4 a4 = *(const float4*)(src + f);
    int r = f >> 8, k = f & 255;
    int slot = (k >> 3) ^ (r & 31);
    *(short4*)&As[(r * 32 + slot) * 8 + (k & 7)] = cvt4(a4);
  }
  __syncthreads();

  float rowacc[8][4];
#pragma unroll
  for (int rt = 0; rt < 8; ++rt)
#pragma unroll
    for (int j = 0; j < 4; ++j) rowacc[rt][j] = 0.f;

#pragma unroll 1
  for (int cc = 0; cc < 4; ++cc) {
    const int nb = cc * 128 + w * 32;  // wave's col base this pass
    bf16x8 breg0[8], breg1[8];
    const short* bp0 = Wbf + (nb + m) * HD + q * 8;
    const short* bp1 = Wbf + (nb + 16 + m) * HD + q * 8;
#pragma unroll
    for (int kk = 0; kk < 8; ++kk) {
      breg0[kk] = *(const bf16x8*)(bp0 + kk * 32);
      breg1[kk] = *(const bf16x8*)(bp1 + kk * 32);
    }
    const float vv0 = vvec[nb + m];
    const float vv1 = vvec[nb + 16 + m];
    // cvecT rows needed: b = (rt&1)*16 + 4q+j
    const f32x4 cva0 = *(const f32x4*)(cvecT + (nb + m) * NB + q * 4);
    const f32x4 cvb0 = *(const f32x4*)(cvecT + (nb + m) * NB + 16 + q * 4);
    const f32x4 cva1 = *(const f32x4*)(cvecT + (nb + 16 + m) * NB + q * 4);
    const f32x4 cvb1 = *(const f32x4*)(cvecT + (nb + 16 + m) * NB + 16 + q * 4);

#pragma unroll
    for (int rt = 0; rt < 8; ++rt) {
      const int r = rt * 16 + m;
      const int rx = r & 31;
      f32x4 acc0 = {0.f, 0.f, 0.f, 0.f}, acc1 = {0.f, 0.f, 0.f, 0.f};
#pragma unroll
      for (int kk = 0; kk < 8; ++kk) {
        bf16x8 a = *(const bf16x8*)&As[(r * 32 + ((kk * 4 + q) ^ rx)) * 8];
        acc0 = __builtin_amdgcn_mfma_f32_16x16x32_bf16(a, breg0[kk], acc0, 0, 0, 0);
        acc1 = __builtin_amdgcn_mfma_f32_16x16x32_bf16(a, breg1[kk], acc1, 0, 0, 0);
      }
      // C/D layout: row = rt*16 + 4q+j, col = n; b = row & 31
      if (rt & 1) {
#pragma unroll
        for (int j = 0; j < 4; ++j)
          rowacc[rt][j] += fast_tanh(acc0[j] + cvb0[j]) * vv0
                         + fast_tanh(acc1[j] + cvb1[j]) * vv1;
      } else {
#pragma unroll
        for (int j = 0; j < 4; ++j)
          rowacc[rt][j] += fast_tanh(acc0[j] + cva0[j]) * vv0
                         + fast_tanh(acc1[j] + cva1[j]) * vv1;
      }
      __builtin_amdgcn_sched_barrier(0);  // keep rt iterations serialized
    }
  }

  // ---- deferred reduction over the 16 m-lanes, then cross-wave combine ----
#pragma unroll
  for (int rt = 0; rt < 8; ++rt) {
#pragma unroll
    for (int j = 0; j < 4; ++j) {
      float e = rowacc[rt][j];
      e += __shfl_xor(e, 1, 64);
      e += __shfl_xor(e, 2, 64);
      e += __shfl_xor(e, 4, 64);
      e += __shfl_xor(e, 8, 64);
      if (m == 0) part[w][rt * 16 + 4 * q + j] = e;
    }
  }
  __syncthreads();
  if (tid < 128) {
    const long r = row0 + tid;  // flat row = t*NB + b
    scores[(r & 31) * NT + (r >> 5)] =
        part[0][tid] + part[1][tid] + part[2][tid] + part[3][tid];
  }
}

// Per batch row: softmax over T (unnormalized exp in LDS), LDS-atomic edge
// scatter, then out = 0.1 * scattered * (1/sum). One block per batch row.
__global__ __launch_bounds__(1024) void softmax_scatter(
    const float* __restrict__ sc, const int* __restrict__ esrc,
    const int* __restrict__ edst, float* __restrict__ out) {
  __shared__ float wsv[NT];
  __shared__ float asv[NT];
  __shared__ float rtmp[16];
  __shared__ float rres;
  const int b = blockIdx.x;
  const int tid = threadIdx.x;
  const int wid = tid >> 6, lane = tid & 63;
  float s[4];
  float mx = -1e30f;
#pragma unroll
  for (int p = 0; p < 4; ++p) {
    s[p] = sc[b * NT + tid + p * 1024];
    mx = fmaxf(mx, s[p]);
  }
#pragma unroll
  for (int d = 32; d >= 1; d >>= 1) mx = fmaxf(mx, __shfl_xor(mx, d, 64));
  if (lane == 0) rtmp[wid] = mx;
  __syncthreads();
  if (tid == 0) {
    float mm = rtmp[0];
#pragma unroll
    for (int i = 1; i < 16; ++i) mm = fmaxf(mm, rtmp[i]);
    rres = mm;
  }
  __syncthreads();
  mx = rres;
  float sm = 0.f;
#pragma unroll
  for (int p = 0; p < 4; ++p) {
    int i = tid + p * 1024;
    float e = __expf(s[p] - mx);
    wsv[i] = e;
    asv[i] = 0.f;
    sm += e;
  }
#pragma unroll
  for (int d = 32; d >= 1; d >>= 1) sm += __shfl_xor(sm, d, 64);
  if (lane == 0) rtmp[wid] = sm;
  __syncthreads();
  if (tid == 0) {
    float tt = 0.f;
#pragma unroll
    for (int i = 0; i < 16; ++i) tt += rtmp[i];
    rres = tt;
  }
  __syncthreads();
  const float inv = 1.0f / rres;

  for (int j = tid; j < NE; j += 1024) {
    int ss = esrc[b * NE + j];
    int dd = edst[b * NE + j];
    if (dd != ss + 1) atomicAdd(&asv[dd], wsv[ss]);
  }
  __syncthreads();
#pragma unroll
  for (int p = 0; p < 4; ++p) {
    int i = tid + p * 1024;
    out[b * NT + i] = 0.1f * asv[i] * inv;
  }
}

extern "C" void kernel_launch(void* const* d_in, const int* in_sizes, int n_in,
                              void* d_out, int out_size, void* d_ws, size_t ws_size,
                              hipStream_t stream) {
  const float* hidden = (const float*)d_in[0];
  const float* enc    = (const float*)d_in[1];
  const int*   esrc   = (const int*)d_in[2];
  const int*   edst   = (const int*)d_in[3];
  const float* Wattn  = (const float*)d_in[4];
  const float* battn  = (const float*)d_in[5];
  const float* vvec   = (const float*)d_in[6];
  float* out = (float*)d_out;

  char* ws = (char*)d_ws;
  float* cvecT  = (float*)ws;                    // 512*32*4   = 64 KB
  short* Wbf    = (short*)(ws + 65536);          // 512*256*2  = 256 KB
  float* scores = (float*)(ws + 65536 + 262144); // 32*4096*4  = 512 KB

  prep<<<384, 256, 0, stream>>>(hidden, Wattn, battn, cvecT, Wbf);
  score_gemm<<<(NB * NT) / 128, 256, 0, stream>>>(enc, Wbf, cvecT, vvec, scores);
  softmax_scatter<<<NB, 1024, 0, stream>>>(scores, esrc, edst, out);
}

// Round 6
// 287.821 us; speedup vs baseline: 1.3550x; 1.0742x over previous
//
#include <hip/hip_runtime.h>
#include <hip/hip_bf16.h>

typedef __attribute__((ext_vector_type(8))) short bf16x8;
typedef __attribute__((ext_vector_type(4))) float f32x4;

#define HD 256   // hidden size (K of the big GEMM)
#define NB 32    // batch
#define NT 4096  // timesteps
#define NE 8192  // edges per graph
#define N2 512   // 2*H (N of the big GEMM)

static __device__ __forceinline__ unsigned short f2bf(float f) {
  unsigned int u = __float_as_uint(f);
  u += 0x7fff + ((u >> 16) & 1);  // round-to-nearest-even
  return (unsigned short)(u >> 16);
}
static __device__ __forceinline__ short4 cvt4(float4 a) {
  return make_short4((short)f2bf(a.x), (short)f2bf(a.y),
                     (short)f2bf(a.z), (short)f2bf(a.w));
}
static __device__ __forceinline__ float fast_tanh(float x) {
  x = fminf(15.f, fmaxf(-15.f, x));
  float e = __expf(x + x);
  return (e - 1.f) * __builtin_amdgcn_rcpf(e + 1.f);
}

// Fused prep:
//  blocks 0..255   : cvecT[n][b] = b_attn[n] + hidden[b] . W_attn[n][0:256]
//  blocks 256..383 : Wbf[n*256+k] = bf16(W_attn[n][256+k])   (one-time convert)
__global__ __launch_bounds__(256) void prep(
    const float* __restrict__ hidden, const float* __restrict__ Wattn,
    const float* __restrict__ battn, float* __restrict__ cvecT,
    short* __restrict__ Wbf) {
  const int tid = threadIdx.x;
  if (blockIdx.x < 256) {
    __shared__ float Ws[64 * 260];
    __shared__ float Hs[HD];
    const int chunk = blockIdx.x & 7;
    const int b = blockIdx.x >> 3;
#pragma unroll
    for (int it = 0; it < 16; ++it) {
      int f = it * 1024 + tid * 4;
      int i = f >> 8, k = f & 255;
      float4 w4 = *(const float4*)(Wattn + (chunk * 64 + i) * N2 + k);
      *(float4*)&Ws[i * 260 + k] = w4;
    }
    if (tid < 64)
      *(float4*)&Hs[tid * 4] = *(const float4*)(hidden + b * HD + tid * 4);
    __syncthreads();
    const int nl = tid >> 2;
    const int kb = (tid & 3) * 64;
    float sum = 0.f;
#pragma unroll
    for (int z = 0; z < 64; z += 4) {
      float4 h4 = *(const float4*)&Hs[kb + z];
      float4 w4 = *(const float4*)&Ws[nl * 260 + kb + z];
      sum = fmaf(h4.x, w4.x, sum);
      sum = fmaf(h4.y, w4.y, sum);
      sum = fmaf(h4.z, w4.z, sum);
      sum = fmaf(h4.w, w4.w, sum);
    }
    sum += __shfl_xor(sum, 1, 64);
    sum += __shfl_xor(sum, 2, 64);
    if ((tid & 3) == 0)
      cvecT[(chunk * 64 + nl) * NB + b] = sum + battn[chunk * 64 + nl];
  } else {
    int f = (blockIdx.x - 256) * 1024 + tid * 4;  // 0..131071 = n*256+k
    int n = f >> 8, k = f & 255;
    float4 w4 = *(const float4*)(Wattn + n * N2 + HD + k);
    *(short4*)(Wbf + f) = cvt4(w4);
  }
}

// scores[b][t] = sum_n v[n]*tanh(cvecT[n][b] + enc_row . Wbf[n])
// 64 rows/block (LDS 33 KB -> up to 4 blocks/CU), 4 col-passes of 32
// cols/wave (breg = 64 VGPRs). sched_barrier(0x0F) per rt-iter: DS/VMEM may
// NOT cross (bounds A-load hoisting = no spill), ALU/MFMA MAY cross (lets
// tanh/MFMA of iter i overlap iter i+1 -> latency hiding R5 lacked).
__global__ __launch_bounds__(256, 1) void score_gemm(
    const float* __restrict__ enc, const short* __restrict__ Wbf,
    const float* __restrict__ cvecT, const float* __restrict__ vvec,
    float* __restrict__ scores) {
  __shared__ short As[64 * 256];  // 32 KB, swizzled
  __shared__ float part[4][64];
  const int tid = threadIdx.x;
  const int w = tid >> 6, lane = tid & 63, q = lane >> 4, m = lane & 15;
  const long row0 = (long)blockIdx.x * 64;

  // ---- stage A (64 rows x 256 k) fp32 -> bf16, swizzled ----
  const float* src = enc + row0 * HD;
#pragma unroll
  for (int it = 0; it < 16; ++it) {
    int f = it * 1024 + tid * 4;
    float4 a4 = *(const float4*)(src + f);
    int r = f >> 8, k = f & 255;
    int slot = (k >> 3) ^ (r & 31);
    *(short4*)&As[(r * 32 + slot) * 8 + (k & 7)] = cvt4(a4);
  }
  __syncthreads();

  float rowacc[4][4];
#pragma unroll
  for (int rt = 0; rt < 4; ++rt)
#pragma unroll
    for (int j = 0; j < 4; ++j) rowacc[rt][j] = 0.f;

#pragma unroll 1
  for (int cc = 0; cc < 4; ++cc) {
    const int nb = cc * 128 + w * 32;  // wave's col base this pass
    bf16x8 breg0[8], breg1[8];
    const short* bp0 = Wbf + (nb + m) * HD + q * 8;
    const short* bp1 = Wbf + (nb + 16 + m) * HD + q * 8;
#pragma unroll
    for (int kk = 0; kk < 8; ++kk) {
      breg0[kk] = *(const bf16x8*)(bp0 + kk * 32);
      breg1[kk] = *(const bf16x8*)(bp1 + kk * 32);
    }
    const float vv0 = vvec[nb + m];
    const float vv1 = vvec[nb + 16 + m];
    // cvecT rows needed: b = (rt&1)*16 + 4q+j
    const f32x4 cva0 = *(const f32x4*)(cvecT + (nb + m) * NB + q * 4);
    const f32x4 cvb0 = *(const f32x4*)(cvecT + (nb + m) * NB + 16 + q * 4);
    const f32x4 cva1 = *(const f32x4*)(cvecT + (nb + 16 + m) * NB + q * 4);
    const f32x4 cvb1 = *(const f32x4*)(cvecT + (nb + 16 + m) * NB + 16 + q * 4);

#pragma unroll
    for (int rt = 0; rt < 4; ++rt) {
      const int r = rt * 16 + m;
      const int rx = r & 31;
      f32x4 acc0 = {0.f, 0.f, 0.f, 0.f}, acc1 = {0.f, 0.f, 0.f, 0.f};
#pragma unroll
      for (int kk = 0; kk < 8; ++kk) {
        bf16x8 a = *(const bf16x8*)&As[(r * 32 + ((kk * 4 + q) ^ rx)) * 8];
        acc0 = __builtin_amdgcn_mfma_f32_16x16x32_bf16(a, breg0[kk], acc0, 0, 0, 0);
        acc1 = __builtin_amdgcn_mfma_f32_16x16x32_bf16(a, breg1[kk], acc1, 0, 0, 0);
      }
      // C/D layout: row = rt*16 + 4q+j, col = n; b = row & 31
      if (rt & 1) {
#pragma unroll
        for (int j = 0; j < 4; ++j)
          rowacc[rt][j] += fast_tanh(acc0[j] + cvb0[j]) * vv0
                         + fast_tanh(acc1[j] + cvb1[j]) * vv1;
      } else {
#pragma unroll
        for (int j = 0; j < 4; ++j)
          rowacc[rt][j] += fast_tanh(acc0[j] + cva0[j]) * vv0
                         + fast_tanh(acc1[j] + cva1[j]) * vv1;
      }
      // ALU/MFMA may cross (overlap), DS/VMEM may not (pressure cap)
      __builtin_amdgcn_sched_barrier(0x0F);
    }
  }

  // ---- deferred reduction over the 16 m-lanes, then cross-wave combine ----
#pragma unroll
  for (int rt = 0; rt < 4; ++rt) {
#pragma unroll
    for (int j = 0; j < 4; ++j) {
      float e = rowacc[rt][j];
      e += __shfl_xor(e, 1, 64);
      e += __shfl_xor(e, 2, 64);
      e += __shfl_xor(e, 4, 64);
      e += __shfl_xor(e, 8, 64);
      if (m == 0) part[w][rt * 16 + 4 * q + j] = e;
    }
  }
  __syncthreads();
  if (tid < 64) {
    const long r = row0 + tid;  // flat row = t*NB + b
    scores[(r & 31) * NT + (r >> 5)] =
        part[0][tid] + part[1][tid] + part[2][tid] + part[3][tid];
  }
}

// Per batch row: softmax over T (unnormalized exp in LDS), LDS-atomic edge
// scatter, then out = 0.1 * scattered * (1/sum). One block per batch row.
__global__ __launch_bounds__(1024) void softmax_scatter(
    const float* __restrict__ sc, const int* __restrict__ esrc,
    const int* __restrict__ edst, float* __restrict__ out) {
  __shared__ float wsv[NT];
  __shared__ float asv[NT];
  __shared__ float rtmp[16];
  __shared__ float rres;
  const int b = blockIdx.x;
  const int tid = threadIdx.x;
  const int wid = tid >> 6, lane = tid & 63;
  float s[4];
  float mx = -1e30f;
#pragma unroll
  for (int p = 0; p < 4; ++p) {
    s[p] = sc[b * NT + tid + p * 1024];
    mx = fmaxf(mx, s[p]);
  }
#pragma unroll
  for (int d = 32; d >= 1; d >>= 1) mx = fmaxf(mx, __shfl_xor(mx, d, 64));
  if (lane == 0) rtmp[wid] = mx;
  __syncthreads();
  if (tid == 0) {
    float mm = rtmp[0];
#pragma unroll
    for (int i = 1; i < 16; ++i) mm = fmaxf(mm, rtmp[i]);
    rres = mm;
  }
  __syncthreads();
  mx = rres;
  float sm = 0.f;
#pragma unroll
  for (int p = 0; p < 4; ++p) {
    int i = tid + p * 1024;
    float e = __expf(s[p] - mx);
    wsv[i] = e;
    asv[i] = 0.f;
    sm += e;
  }
#pragma unroll
  for (int d = 32; d >= 1; d >>= 1) sm += __shfl_xor(sm, d, 64);
  if (lane == 0) rtmp[wid] = sm;
  __syncthreads();
  if (tid == 0) {
    float tt = 0.f;
#pragma unroll
    for (int i = 0; i < 16; ++i) tt += rtmp[i];
    rres = tt;
  }
  __syncthreads();
  const float inv = 1.0f / rres;

  for (int j = tid; j < NE; j += 1024) {
    int ss = esrc[b * NE + j];
    int dd = edst[b * NE + j];
    if (dd != ss + 1) atomicAdd(&asv[dd], wsv[ss]);
  }
  __syncthreads();
#pragma unroll
  for (int p = 0; p < 4; ++p) {
    int i = tid + p * 1024;
    out[b * NT + i] = 0.1f * asv[i] * inv;
  }
}

extern "C" void kernel_launch(void* const* d_in, const int* in_sizes, int n_in,
                              void* d_out, int out_size, void* d_ws, size_t ws_size,
                              hipStream_t stream) {
  const float* hidden = (const float*)d_in[0];
  const float* enc    = (const float*)d_in[1];
  const int*   esrc   = (const int*)d_in[2];
  const int*   edst   = (const int*)d_in[3];
  const float* Wattn  = (const float*)d_in[4];
  const float* battn  = (const float*)d_in[5];
  const float* vvec   = (const float*)d_in[6];
  float* out = (float*)d_out;

  char* ws = (char*)d_ws;
  float* cvecT  = (float*)ws;                    // 512*32*4   = 64 KB
  short* Wbf    = (short*)(ws + 65536);          // 512*256*2  = 256 KB
  float* scores = (float*)(ws + 65536 + 262144); // 32*4096*4  = 512 KB

  prep<<<384, 256, 0, stream>>>(hidden, Wattn, battn, cvecT, Wbf);
  score_gemm<<<(NB * NT) / 64, 256, 0, stream>>>(enc, Wbf, cvecT, vvec, scores);
  softmax_scatter<<<NB, 1024, 0, stream>>>(scores, esrc, edst, out);
}